// Round 1
// baseline (612.017 us; speedup 1.0000x reference)
//
#include <hip/hip_runtime.h>
#include <math.h>

static constexpr int M_ROWS   = 200000;
static constexpr int NUM_NODE = 150;
static constexpr int ROWS_PER_BLOCK = 4;   // one wave (64 lanes) per row

__global__ __launch_bounds__(256) void obstacle_to_lane_kernel(
    const float* __restrict__ lf,       // (M, 150, 4) f32
    const float* __restrict__ obs_pos,  // (N, 2) f32
    const int*   __restrict__ mask,     // (M, 1) i32
    float*       __restrict__ out)      // [M*2 proj | M*2 idx | M*2 rep]
{
    const int wave = threadIdx.x >> 6;
    const int lane = threadIdx.x & 63;
    const int m = blockIdx.x * ROWS_PER_BLOCK + wave;
    if (m >= M_ROWS) return;

    const float* row = lf + (size_t)m * (NUM_NODE * 4);

    const int obs_idx = mask[m];
    const float rx = obs_pos[2 * obs_idx];
    const float ry = obs_pos[2 * obs_idx + 1];

    // ---- argmin over nodes 1..148 of (x-rx)^2 + (y-ry)^2 ----
    float best_d = INFINITY;
    int   best_j = 1 << 30;
    #pragma unroll
    for (int r = 0; r < 3; ++r) {
        const int j = 1 + lane + r * 64;
        if (j <= NUM_NODE - 2) {
            const float4 n = *reinterpret_cast<const float4*>(row + 4 * j);
            const float dx = __fsub_rn(n.x, rx);
            const float dy = __fsub_rn(n.y, ry);
            const float d  = __fadd_rn(__fmul_rn(dx, dx), __fmul_rn(dy, dy));
            // strict < keeps the first (lowest-j) occurrence within a lane
            if (d < best_d) { best_d = d; best_j = j; }
        }
    }
    // wave-wide argmin reduction (64 lanes); ties -> smaller index (jnp.argmin semantics)
    #pragma unroll
    for (int off = 32; off > 0; off >>= 1) {
        const float od = __shfl_down(best_d, off, 64);
        const int   oj = __shfl_down(best_j, off, 64);
        if (od < best_d || (od == best_d && oj < best_j)) { best_d = od; best_j = oj; }
    }
    const int min_idx = __shfl(best_j, 0, 64);

    if (lane == 0) {
        // neighbor rows are in L1/L2 (just loaded by this wave) — cheap re-read
        const float4 a = *reinterpret_cast<const float4*>(row + 4 * (min_idx - 1));
        const float4 c = *reinterpret_cast<const float4*>(row + 4 * min_idx);
        const float4 b = *reinterpret_cast<const float4*>(row + 4 * (min_idx + 1));

        // dist_prev / dist_next over all 4 features, numpy left-to-right order, no FMA contraction
        float t, s;
        t = __fsub_rn(a.x, c.x); s = __fmul_rn(t, t);
        t = __fsub_rn(a.y, c.y); s = __fadd_rn(s, __fmul_rn(t, t));
        t = __fsub_rn(a.z, c.z); s = __fadd_rn(s, __fmul_rn(t, t));
        t = __fsub_rn(a.w, c.w); s = __fadd_rn(s, __fmul_rn(t, t));
        const float dist_prev = s;
        t = __fsub_rn(b.x, c.x); s = __fmul_rn(t, t);
        t = __fsub_rn(b.y, c.y); s = __fadd_rn(s, __fmul_rn(t, t));
        t = __fsub_rn(b.z, c.z); s = __fadd_rn(s, __fmul_rn(t, t));
        t = __fsub_rn(b.w, c.w); s = __fadd_rn(s, __fmul_rn(t, t));
        const float dist_next = s;

        float sx, sy, ex, ey;
        int ib;
        if (dist_next < dist_prev) {            // 2nd = min_idx+1 -> before=min_idx, after=min_idx+1
            ib = min_idx;     sx = c.x; sy = c.y; ex = b.x; ey = b.y;
        } else {                                // 2nd = min_idx-1 -> before=min_idx-1, after=min_idx
            ib = min_idx - 1; sx = a.x; sy = a.y; ex = c.x; ey = c.y;
        }

        const float lvx = __fsub_rn(ex, sx);
        const float lvy = __fsub_rn(ey, sy);
        const float mag = __fsqrt_rn(__fadd_rn(__fmul_rn(lvx, lvx), __fmul_rn(lvy, lvy)));
        const float ux  = __fdiv_rn(lvx, mag);
        const float uy  = __fdiv_rn(lvy, mag);
        const float pm  = __fadd_rn(__fmul_rn(__fsub_rn(rx, sx), ux),
                                    __fmul_rn(__fsub_rn(ry, sy), uy));
        const float px  = __fadd_rn(sx, __fmul_rn(pm, ux));
        const float py  = __fadd_rn(sy, __fmul_rn(pm, uy));

        float* o_proj = out + 2 * (size_t)m;
        o_proj[0] = px; o_proj[1] = py;
        float* o_idx = out + 2 * (size_t)M_ROWS + 2 * (size_t)m;
        o_idx[0] = (float)ib; o_idx[1] = (float)(ib + 1);
        float* o_rep = out + 4 * (size_t)M_ROWS + 2 * (size_t)m;
        o_rep[0] = rx; o_rep[1] = ry;
    }
}

extern "C" void kernel_launch(void* const* d_in, const int* in_sizes, int n_in,
                              void* d_out, int out_size, void* d_ws, size_t ws_size,
                              hipStream_t stream) {
    const float* lf      = (const float*)d_in[0];
    const float* obs_pos = (const float*)d_in[1];
    const int*   mask    = (const int*)d_in[2];
    float*       out     = (float*)d_out;

    const int grid = (M_ROWS + ROWS_PER_BLOCK - 1) / ROWS_PER_BLOCK;  // 50000
    hipLaunchKernelGGL(obstacle_to_lane_kernel, dim3(grid), dim3(256), 0, stream,
                       lf, obs_pos, mask, out);
}